// Round 1
// baseline (334.961 us; speedup 1.0000x reference)
//
#include <hip/hip_runtime.h>

#define DEV __device__ __forceinline__

typedef __bf16 bf16x8 __attribute__((ext_vector_type(8)));
typedef float f32x4 __attribute__((ext_vector_type(4)));

constexpr int S_LEN = 2048;
constexpr int DMODEL = 1024;
constexpr int NHEAD = 16;
constexpr int HDIM = 64;
constexpr int BATCH = 2;
constexpr int MROWS = BATCH * S_LEN;  // 4096

DEV short f2bf(float x) {
  unsigned u = __builtin_bit_cast(unsigned, x);
  unsigned r = u + 0x7fffu + ((u >> 16) & 1u);
  return (short)(r >> 16);
}

#define MFMA16(a, b, c) __builtin_amdgcn_mfma_f32_16x16x32_bf16((a), (b), (c), 0, 0, 0)
#define GLL16(g, l)                                                                     \
  __builtin_amdgcn_global_load_lds((const __attribute__((address_space(1))) void*)(g),  \
                                   (__attribute__((address_space(3))) void*)(l), 16, 0, 0)

// ---------------- fp32 -> bf16 convert (vectorized) ----------------
__global__ void cvt_kernel(const float* __restrict__ in, short* __restrict__ out, int n) {
  int i = (blockIdx.x * blockDim.x + threadIdx.x) * 4;
  const int stride = gridDim.x * blockDim.x * 4;
  for (; i < n; i += stride) {
    float4 v = *(const float4*)&in[i];
    short4 r;
    r.x = f2bf(v.x);
    r.y = f2bf(v.y);
    r.z = f2bf(v.z);
    r.w = f2bf(v.w);
    *(short4*)&out[i] = r;
  }
}

// ---------------- bf16 GEMM: C[m,e] = sum_k A[m,k] * Bt[e,k] ----------------
// 128x128 tile, BK=32, 4 waves (2x2), each wave 64x64 via 4x4 frags of 16x16x32 MFMA.
// mode 0: Q epilogue (scale 1/8, layout [B,H,S,HD] bf16)
// mode 1: K epilogue (layout [B,H,S,HD] bf16)
// mode 2: V epilogue (layout [B,H,HD,S] bf16, transposed)
// mode 3: out epilogue (fp32 [M,N] + bias)
__global__ __launch_bounds__(256) void gemm_bt(const short* __restrict__ A,
                                               const short* __restrict__ Bt,
                                               short* __restrict__ outb,
                                               float* __restrict__ outf,
                                               const float* __restrict__ bias,
                                               const int mode) {
  constexpr int K = DMODEL;
  constexpr int N = DMODEL;
  __shared__ short As[128 * 32];
  __shared__ short Bs[128 * 32];
  const int tid = threadIdx.x;
  const int w = tid >> 6, l = tid & 63;
  const int lr = l & 15, lh = l >> 4;
  const int wr = w >> 1, wc = w & 1;
  const int tm = blockIdx.x, tn = blockIdx.y;

  f32x4 acc[4][4] = {};

  for (int kt = 0; kt < K / 32; ++kt) {
#pragma unroll
    for (int r = 0; r < 2; ++r) {
      const int c = r * 256 + tid;
      const int row = c >> 2;
      const int kc = (c & 3) * 8;
      GLL16(A + (size_t)(tm * 128 + row) * K + kt * 32 + kc, &As[(r * 256 + w * 64) * 8]);
      GLL16(Bt + (size_t)(tn * 128 + row) * K + kt * 32 + kc, &Bs[(r * 256 + w * 64) * 8]);
    }
    __syncthreads();
    bf16x8 af[4], bfr[4];
#pragma unroll
    for (int mi = 0; mi < 4; ++mi)
      af[mi] = *(const bf16x8*)&As[(wr * 64 + mi * 16 + lr) * 32 + lh * 8];
#pragma unroll
    for (int ni = 0; ni < 4; ++ni)
      bfr[ni] = *(const bf16x8*)&Bs[(wc * 64 + ni * 16 + lr) * 32 + lh * 8];
#pragma unroll
    for (int mi = 0; mi < 4; ++mi)
#pragma unroll
      for (int ni = 0; ni < 4; ++ni)
        acc[mi][ni] = MFMA16(af[mi], bfr[ni], acc[mi][ni]);
    __syncthreads();
  }

  // Epilogue. C/D frag layout: row = (l>>4)*4 + i, col = l&15  [verified m89/m91]
  const int m0 = tm * 128 + wr * 64;
  const int n0 = tn * 128 + wc * 64;
  if (mode == 3) {
#pragma unroll
    for (int mi = 0; mi < 4; ++mi)
#pragma unroll
      for (int ni = 0; ni < 4; ++ni)
#pragma unroll
        for (int i = 0; i < 4; ++i) {
          const int m = m0 + mi * 16 + lh * 4 + i;
          const int e = n0 + ni * 16 + lr;
          outf[(size_t)m * N + e] = acc[mi][ni][i] + bias[e];
        }
  } else if (mode == 2) {
#pragma unroll
    for (int mi = 0; mi < 4; ++mi)
#pragma unroll
      for (int ni = 0; ni < 4; ++ni)
#pragma unroll
        for (int i = 0; i < 4; ++i) {
          const int m = m0 + mi * 16 + lh * 4 + i;
          const int e = n0 + ni * 16 + lr;
          const int b = m >> 11, n = m & (S_LEN - 1);
          const int h = e >> 6, d = e & (HDIM - 1);
          outb[((size_t)((b * NHEAD + h) * HDIM + d)) * S_LEN + n] = f2bf(acc[mi][ni][i]);
        }
  } else {
    const float sc = (mode == 0) ? 0.125f : 1.0f;
#pragma unroll
    for (int mi = 0; mi < 4; ++mi)
#pragma unroll
      for (int ni = 0; ni < 4; ++ni)
#pragma unroll
        for (int i = 0; i < 4; ++i) {
          const int m = m0 + mi * 16 + lh * 4 + i;
          const int e = n0 + ni * 16 + lr;
          const int b = m >> 11, n = m & (S_LEN - 1);
          const int h = e >> 6, d = e & (HDIM - 1);
          outb[((size_t)((b * NHEAD + h) * S_LEN + n)) * HDIM + d] = f2bf(acc[mi][ni][i] * sc);
        }
  }
}

// ---------------- flash attention ----------------
// grid: (S/64, B*H). 4 waves/block; wave w owns 16 q-rows. KV tiles of 32.
// Q pre-scaled by 1/8. K layout [B,H,S,HD]; V layout [B,H,HD,S] (transposed).
__global__ __launch_bounds__(256) void attn_kernel(const short* __restrict__ Qg,
                                                   const short* __restrict__ Kg,
                                                   const short* __restrict__ Vg,
                                                   short* __restrict__ ctx) {
  __shared__ short plds[4][16 * 32];
  const int w = threadIdx.x >> 6;
  const int l = threadIdx.x & 63;
  const int lr = l & 15;
  const int lh = l >> 4;
  const int bh = blockIdx.y;
  const int qbase = blockIdx.x * 64 + w * 16;
  const short* Qh = Qg + (size_t)bh * S_LEN * HDIM;
  const short* Kh = Kg + (size_t)bh * S_LEN * HDIM;
  const short* Vh = Vg + (size_t)bh * HDIM * S_LEN;

  // A-operand fragment of Q: lane holds Q[qbase + (l&15)][(l>>4)*8 + j], two K=32 chunks
  const bf16x8 qf0 = *(const bf16x8*)&Qh[(size_t)(qbase + lr) * HDIM + lh * 8];
  const bf16x8 qf1 = *(const bf16x8*)&Qh[(size_t)(qbase + lr) * HDIM + 32 + lh * 8];

  f32x4 o0 = {0.f, 0.f, 0.f, 0.f}, o1 = {0.f, 0.f, 0.f, 0.f};
  f32x4 o2 = {0.f, 0.f, 0.f, 0.f}, o3 = {0.f, 0.f, 0.f, 0.f};
  float mrow[4], lrow[4];
#pragma unroll
  for (int i = 0; i < 4; ++i) {
    mrow[i] = -__builtin_inff();
    lrow[i] = 0.f;
  }

  short* pl = plds[w];
  const int tmax = (qbase + 15) >> 5;  // inclusive
  for (int t = 0; t <= tmax; ++t) {
    const int kv0 = t * 32;
    const short* Kt = Kh + (size_t)kv0 * HDIM;
    // B-operand of K^T: lane holds K[kv0 + cb*16 + (l&15)][(l>>4)*8 + j]
    bf16x8 k00 = *(const bf16x8*)&Kt[(size_t)lr * HDIM + lh * 8];
    bf16x8 k01 = *(const bf16x8*)&Kt[(size_t)lr * HDIM + 32 + lh * 8];
    bf16x8 k10 = *(const bf16x8*)&Kt[(size_t)(16 + lr) * HDIM + lh * 8];
    bf16x8 k11 = *(const bf16x8*)&Kt[(size_t)(16 + lr) * HDIM + 32 + lh * 8];
    f32x4 s0 = {0.f, 0.f, 0.f, 0.f}, s1 = {0.f, 0.f, 0.f, 0.f};
    s0 = MFMA16(qf0, k00, s0);
    s0 = MFMA16(qf1, k01, s0);
    s1 = MFMA16(qf0, k10, s1);
    s1 = MFMA16(qf1, k11, s1);

    // causal mask + per-row max (C layout: row = lh*4+i, col = lr)
    float pm[4];
#pragma unroll
    for (int i = 0; i < 4; ++i) {
      const int qrow = qbase + lh * 4 + i;
      if (kv0 + lr > qrow) s0[i] = -__builtin_inff();
      if (kv0 + 16 + lr > qrow) s1[i] = -__builtin_inff();
      pm[i] = fmaxf(s0[i], s1[i]);
    }
#pragma unroll
    for (int d = 1; d < 16; d <<= 1) {
#pragma unroll
      for (int i = 0; i < 4; ++i) pm[i] = fmaxf(pm[i], __shfl_xor(pm[i], d));
    }
    float f[4], ps[4];
#pragma unroll
    for (int i = 0; i < 4; ++i) {
      const float nm = fmaxf(mrow[i], pm[i]);
      f[i] = expf(mrow[i] - nm);
      mrow[i] = nm;
      s0[i] = expf(s0[i] - nm);
      s1[i] = expf(s1[i] - nm);
      ps[i] = s0[i] + s1[i];
    }
#pragma unroll
    for (int d = 1; d < 16; d <<= 1) {
#pragma unroll
      for (int i = 0; i < 4; ++i) ps[i] += __shfl_xor(ps[i], d);
    }
#pragma unroll
    for (int i = 0; i < 4; ++i) {
      lrow[i] = lrow[i] * f[i] + ps[i];
      o0[i] *= f[i];
      o1[i] *= f[i];
      o2[i] *= f[i];
      o3[i] *= f[i];
      // P (C-layout) -> LDS as bf16
      pl[(lh * 4 + i) * 32 + lr] = f2bf(s0[i]);
      pl[(lh * 4 + i) * 32 + 16 + lr] = f2bf(s1[i]);
    }
    asm volatile("s_waitcnt lgkmcnt(0)" ::: "memory");
    // read back in A-operand layout: P[l&15][(l>>4)*8 + j]
    const bf16x8 pf = *(const bf16x8*)&pl[lr * 32 + lh * 8];
    // V (B-operand): V[kv0 + (l>>4)*8 + j][nb*16 + (l&15)] = VT[nb*16+lr][kv0 + lh*8 + j]
    const short* Vt = Vh + kv0;
    bf16x8 v0f = *(const bf16x8*)&Vt[(size_t)lr * S_LEN + lh * 8];
    bf16x8 v1f = *(const bf16x8*)&Vt[(size_t)(16 + lr) * S_LEN + lh * 8];
    bf16x8 v2f = *(const bf16x8*)&Vt[(size_t)(32 + lr) * S_LEN + lh * 8];
    bf16x8 v3f = *(const bf16x8*)&Vt[(size_t)(48 + lr) * S_LEN + lh * 8];
    o0 = MFMA16(pf, v0f, o0);
    o1 = MFMA16(pf, v1f, o1);
    o2 = MFMA16(pf, v2f, o2);
    o3 = MFMA16(pf, v3f, o3);
  }

  const int b = bh >> 4, h = bh & (NHEAD - 1);
#pragma unroll
  for (int i = 0; i < 4; ++i) {
    const float inv = 1.0f / lrow[i];
    const size_t base = (size_t)(b * S_LEN + qbase + lh * 4 + i) * DMODEL + h * HDIM + lr;
    ctx[base] = f2bf(o0[i] * inv);
    ctx[base + 16] = f2bf(o1[i] * inv);
    ctx[base + 32] = f2bf(o2[i] * inv);
    ctx[base + 48] = f2bf(o3[i] * inv);
  }
}

extern "C" void kernel_launch(void* const* d_in, const int* in_sizes, int n_in,
                              void* d_out, int out_size, void* d_ws, size_t ws_size,
                              hipStream_t stream) {
  const float* x = (const float*)d_in[0];
  const float* Wq = (const float*)d_in[1];
  const float* Wk = (const float*)d_in[2];
  const float* Wv = (const float*)d_in[3];
  const float* Wo = (const float*)d_in[4];
  const float* bo = (const float*)d_in[5];

  const size_t XN = (size_t)MROWS * DMODEL;   // 4096*1024
  const size_t WN = (size_t)DMODEL * DMODEL;  // 1024*1024

  short* ws = (short*)d_ws;
  short* xb = ws;
  short* Wqb = xb + XN;
  short* Wkb = Wqb + WN;
  short* Wvb = Wkb + WN;
  short* Wob = Wvb + WN;
  short* Qb = Wob + WN;
  short* Kb = Qb + XN;
  short* Vb = Kb + XN;
  short* ctxb = Vb + XN;
  // total: 5*XN + 4*WN shorts = 48 MiB
  if (ws_size < (5 * XN + 4 * WN) * sizeof(short)) return;

  cvt_kernel<<<2048, 256, 0, stream>>>(x, xb, (int)XN);
  cvt_kernel<<<1024, 256, 0, stream>>>(Wq, Wqb, (int)WN);
  cvt_kernel<<<1024, 256, 0, stream>>>(Wk, Wkb, (int)WN);
  cvt_kernel<<<1024, 256, 0, stream>>>(Wv, Wvb, (int)WN);
  cvt_kernel<<<1024, 256, 0, stream>>>(Wo, Wob, (int)WN);

  dim3 gg(MROWS / 128, DMODEL / 128);  // 32 x 8
  gemm_bt<<<gg, 256, 0, stream>>>(xb, Wqb, Qb, nullptr, nullptr, 0);
  gemm_bt<<<gg, 256, 0, stream>>>(xb, Wkb, Kb, nullptr, nullptr, 1);
  gemm_bt<<<gg, 256, 0, stream>>>(xb, Wvb, Vb, nullptr, nullptr, 2);

  attn_kernel<<<dim3(S_LEN / 64, BATCH * NHEAD), 256, 0, stream>>>(Qb, Kb, Vb, ctxb);

  gemm_bt<<<gg, 256, 0, stream>>>(ctxb, Wob, nullptr, (float*)d_out, bo, 3);
}

// Round 2
// 226.288 us; speedup vs baseline: 1.4802x; 1.4802x over previous
//
#include <hip/hip_runtime.h>

#define DEV __device__ __forceinline__

typedef __bf16 bf16x8 __attribute__((ext_vector_type(8)));
typedef float f32x4 __attribute__((ext_vector_type(4)));
typedef float f32x16 __attribute__((ext_vector_type(16)));
typedef unsigned u32x4 __attribute__((ext_vector_type(4)));

constexpr int S_LEN = 2048;
constexpr int DMODEL = 1024;
constexpr int NHEAD = 16;
constexpr int HDIM = 64;
constexpr int BATCH = 2;
constexpr int MROWS = BATCH * S_LEN;  // 4096
constexpr float QSCALE = 0.125f * 1.44269504088896f;  // 1/sqrt(64) * log2(e)

DEV short f2bf(float x) {
  unsigned u = __builtin_bit_cast(unsigned, x);
  unsigned r = u + 0x7fffu + ((u >> 16) & 1u);
  return (short)(r >> 16);
}

#define MFMA16(a, b, c) __builtin_amdgcn_mfma_f32_16x16x32_bf16((a), (b), (c), 0, 0, 0)
#define MFMA32(a, b, c) __builtin_amdgcn_mfma_f32_32x32x16_bf16((a), (b), (c), 0, 0, 0)
#define GLL16(g, l)                                                                     \
  __builtin_amdgcn_global_load_lds((const __attribute__((address_space(1))) void*)(g),  \
                                   (__attribute__((address_space(3))) void*)(l), 16, 0, 0)

DEV unsigned cvt_pk_bf16(float a, float b) {
  unsigned r;
  asm("v_cvt_pk_bf16_f32 %0, %1, %2" : "=v"(r) : "v"(a), "v"(b));
  return r;
}
DEV void swap32(unsigned& a, unsigned& b) {
  asm("v_permlane32_swap_b32 %0, %1" : "+v"(a), "+v"(b));
}

// ---------------- fp32 -> bf16 converts ----------------
__global__ void cvt_kernel(const float* __restrict__ in, short* __restrict__ out, int n) {
  int i = (blockIdx.x * blockDim.x + threadIdx.x) * 4;
  const int stride = gridDim.x * blockDim.x * 4;
  for (; i < n; i += stride) {
    float4 v = *(const float4*)&in[i];
    short4 r;
    r.x = f2bf(v.x);
    r.y = f2bf(v.y);
    r.z = f2bf(v.z);
    r.w = f2bf(v.w);
    *(short4*)&out[i] = r;
  }
}

__global__ void cvt_w4(const float* __restrict__ Wq, const float* __restrict__ Wk,
                       const float* __restrict__ Wv, const float* __restrict__ Wo,
                       short* __restrict__ out) {
  const float* src = blockIdx.y == 0 ? Wq : blockIdx.y == 1 ? Wk : blockIdx.y == 2 ? Wv : Wo;
  short* dst = out + (size_t)blockIdx.y * (DMODEL * DMODEL);
  int i = (blockIdx.x * blockDim.x + threadIdx.x) * 4;
  const int stride = gridDim.x * blockDim.x * 4;
  for (; i < DMODEL * DMODEL; i += stride) {
    float4 v = *(const float4*)&src[i];
    short4 r;
    r.x = f2bf(v.x);
    r.y = f2bf(v.y);
    r.z = f2bf(v.z);
    r.w = f2bf(v.w);
    *(short4*)&dst[i] = r;
  }
}

// ---------------- bf16 GEMM: C[m,e] = sum_k A[m,k] * Bt[e,k] ----------------
// mode 3: out epilogue (fp32 [M,N] + bias)
// mode 4: fused QKV epilogue (Bt is [Wq;Wk;Wv] 3072x1024; outb = Q base, K/V follow)
__global__ __launch_bounds__(256) void gemm_bt(const short* __restrict__ A,
                                               const short* __restrict__ Bt,
                                               short* __restrict__ outb,
                                               float* __restrict__ outf,
                                               const float* __restrict__ bias,
                                               const int mode) {
  constexpr int K = DMODEL;
  constexpr int N = DMODEL;
  constexpr size_t XN = (size_t)MROWS * DMODEL;
  __shared__ short As[128 * 32];
  __shared__ short Bs[128 * 32];
  const int tid = threadIdx.x;
  const int w = tid >> 6, l = tid & 63;
  const int lr = l & 15, lh = l >> 4;
  const int wr = w >> 1, wc = w & 1;
  const int tm = blockIdx.x, tn = blockIdx.y;

  f32x4 acc[4][4] = {};

  for (int kt = 0; kt < K / 32; ++kt) {
#pragma unroll
    for (int r = 0; r < 2; ++r) {
      const int c = r * 256 + tid;
      const int row = c >> 2;
      const int kc = (c & 3) * 8;
      GLL16(A + (size_t)(tm * 128 + row) * K + kt * 32 + kc, &As[(r * 256 + w * 64) * 8]);
      GLL16(Bt + (size_t)(tn * 128 + row) * K + kt * 32 + kc, &Bs[(r * 256 + w * 64) * 8]);
    }
    __syncthreads();
    bf16x8 af[4], bfr[4];
#pragma unroll
    for (int mi = 0; mi < 4; ++mi)
      af[mi] = *(const bf16x8*)&As[(wr * 64 + mi * 16 + lr) * 32 + lh * 8];
#pragma unroll
    for (int ni = 0; ni < 4; ++ni)
      bfr[ni] = *(const bf16x8*)&Bs[(wc * 64 + ni * 16 + lr) * 32 + lh * 8];
#pragma unroll
    for (int mi = 0; mi < 4; ++mi)
#pragma unroll
      for (int ni = 0; ni < 4; ++ni)
        acc[mi][ni] = MFMA16(af[mi], bfr[ni], acc[mi][ni]);
    __syncthreads();
  }

  // C/D frag layout: row = (l>>4)*4 + i, col = l&15
  const int m0 = tm * 128 + wr * 64;
  const int n0 = tn * 128 + wc * 64;
  if (mode == 3) {
#pragma unroll
    for (int mi = 0; mi < 4; ++mi)
#pragma unroll
      for (int ni = 0; ni < 4; ++ni)
#pragma unroll
        for (int i = 0; i < 4; ++i) {
          const int m = m0 + mi * 16 + lh * 4 + i;
          const int e = n0 + ni * 16 + lr;
          outf[(size_t)m * N + e] = acc[mi][ni][i] + bias[e];
        }
  } else {  // fused QKV
    const int sel = tn >> 3;
#pragma unroll
    for (int mi = 0; mi < 4; ++mi)
#pragma unroll
      for (int ni = 0; ni < 4; ++ni)
#pragma unroll
        for (int i = 0; i < 4; ++i) {
          const int m = m0 + mi * 16 + lh * 4 + i;
          const int e = n0 + ni * 16 + lr;
          const int ecol = e & (DMODEL - 1);
          const int b = m >> 11, n = m & (S_LEN - 1);
          const int h = ecol >> 6, d = ecol & (HDIM - 1);
          if (sel == 0)
            outb[((size_t)((b * NHEAD + h) * S_LEN + n)) * HDIM + d] =
                f2bf(acc[mi][ni][i] * QSCALE);
          else if (sel == 1)
            (outb + XN)[((size_t)((b * NHEAD + h) * S_LEN + n)) * HDIM + d] =
                f2bf(acc[mi][ni][i]);
          else
            (outb + 2 * XN)[((size_t)((b * NHEAD + h) * HDIM + d)) * S_LEN + n] =
                f2bf(acc[mi][ni][i]);
        }
  }
}

// ---------------- flash attention, swapped-QK^T 32x32 structure ----------------
// grid: (S/128, B*H), 4 waves/block; wave owns 32 q rows. KV tile = 32.
// Q pre-scaled by log2(e)/8. K layout [B,H,S,HD]; V layout [B,H,HD,S].
// S^T = mfma(A=K, B=Q): lane holds col q = qbase+(l&31), rows k = crow(r,h5).
__global__ __launch_bounds__(256) void attn_kernel(const short* __restrict__ Qg,
                                                   const short* __restrict__ Kg,
                                                   const short* __restrict__ Vg,
                                                   short* __restrict__ ctx) {
  const int w = threadIdx.x >> 6;
  const int l = threadIdx.x & 63;
  const int lq = l & 31;
  const int h5 = l >> 5;
  const int bh = blockIdx.y;
  const int qbase = (gridDim.x - 1 - blockIdx.x) * 128 + w * 32;  // big blocks first
  const short* Qh = Qg + (size_t)bh * (S_LEN * HDIM);
  const short* Kh = Kg + (size_t)bh * (S_LEN * HDIM);
  const short* Vh = Vg + (size_t)bh * (HDIM * S_LEN);

  // Q as B-operand: lane holds Q[qbase+lq][c*16 + h5*8 + j]
  bf16x8 qf[4];
#pragma unroll
  for (int c = 0; c < 4; ++c)
    qf[c] = *(const bf16x8*)&Qh[(size_t)(qbase + lq) * HDIM + c * 16 + h5 * 8];

  f32x16 o0 = {}, o1 = {};
  float m = -__builtin_inff(), ll = 0.f;

  // one softmax+PV tile (closes over o0,o1,m,ll,qf)
  auto tile = [&](bool mask, bf16x8 kf0, bf16x8 kf1, bf16x8 kf2, bf16x8 kf3, bf16x8 v00,
                  bf16x8 v01, bf16x8 v10, bf16x8 v11) {
    f32x16 st = {};
    st = MFMA32(kf0, qf[0], st);
    st = MFMA32(kf1, qf[1], st);
    st = MFMA32(kf2, qf[2], st);
    st = MFMA32(kf3, qf[3], st);
    if (mask) {  // diagonal tile: k-row kr masked iff kr > lq
#pragma unroll
      for (int r = 0; r < 16; ++r) {
        const int kr = (r & 3) + 8 * (r >> 2) + 4 * h5;
        if (kr > lq) st[r] = -__builtin_inff();
      }
    }
    float pm = st[0];
#pragma unroll
    for (int r = 1; r < 16; ++r) pm = fmaxf(pm, st[r]);
    pm = fmaxf(pm, __shfl_xor(pm, 32));
    if (__any(pm - m > 8.f)) {  // defer-max: rescale only when needed
      const float nm = fmaxf(m, pm);
      const float f = __builtin_amdgcn_exp2f(m - nm);
      m = nm;
      ll *= f;
#pragma unroll
      for (int r = 0; r < 16; ++r) {
        const int srcb = ((r & 3) + 8 * (r >> 2) + 4 * h5) << 2;
        const float fr = __builtin_bit_cast(
            float, __builtin_amdgcn_ds_bpermute(srcb, __builtin_bit_cast(int, f)));
        o0[r] *= fr;
        o1[r] *= fr;
      }
    }
    float ps = 0.f;
#pragma unroll
    for (int r = 0; r < 16; ++r) {
      st[r] = __builtin_amdgcn_exp2f(st[r] - m);
      ps += st[r];
    }
    ps += __shfl_xor(ps, 32);
    ll += ps;
    // pack P -> A-operand frags: cvt_pk pairs + permlane32_swap (hi(dst)<->lo(src))
    unsigned a0 = cvt_pk_bf16(st[0], st[1]), b0 = cvt_pk_bf16(st[4], st[5]);
    unsigned a1 = cvt_pk_bf16(st[2], st[3]), b1 = cvt_pk_bf16(st[6], st[7]);
    unsigned a2 = cvt_pk_bf16(st[8], st[9]), b2 = cvt_pk_bf16(st[12], st[13]);
    unsigned a3 = cvt_pk_bf16(st[10], st[11]), b3 = cvt_pk_bf16(st[14], st[15]);
    swap32(a0, b0);
    swap32(a1, b1);
    swap32(a2, b2);
    swap32(a3, b3);
    const u32x4 pw0 = {a0, a1, b0, b1};
    const u32x4 pw1 = {a2, a3, b2, b3};
    const bf16x8 pa0 = __builtin_bit_cast(bf16x8, pw0);
    const bf16x8 pa1 = __builtin_bit_cast(bf16x8, pw1);
    o0 = MFMA32(pa0, v00, o0);
    o0 = MFMA32(pa1, v01, o0);
    o1 = MFMA32(pa0, v10, o1);
    o1 = MFMA32(pa1, v11, o1);
  };

#define LOADKV(T, k0, k1, k2, k3, va, vb, vc, vd)                              \
  {                                                                            \
    const short* Kt = Kh + (size_t)(T) * (32 * HDIM);                          \
    k0 = *(const bf16x8*)&Kt[(size_t)lq * HDIM + h5 * 8];                      \
    k1 = *(const bf16x8*)&Kt[(size_t)lq * HDIM + 16 + h5 * 8];                 \
    k2 = *(const bf16x8*)&Kt[(size_t)lq * HDIM + 32 + h5 * 8];                 \
    k3 = *(const bf16x8*)&Kt[(size_t)lq * HDIM + 48 + h5 * 8];                 \
    const short* Vt = Vh + (size_t)(T) * 32;                                   \
    va = *(const bf16x8*)&Vt[(size_t)lq * S_LEN + h5 * 8];                     \
    vb = *(const bf16x8*)&Vt[(size_t)lq * S_LEN + 16 + h5 * 8];                \
    vc = *(const bf16x8*)&Vt[(size_t)(32 + lq) * S_LEN + h5 * 8];              \
    vd = *(const bf16x8*)&Vt[(size_t)(32 + lq) * S_LEN + 16 + h5 * 8];         \
  }

  const int tmax = qbase >> 5;
  bf16x8 ka0, ka1, ka2, ka3, vA0, vA1, vA2, vA3;
  bf16x8 kb0, kb1, kb2, kb3, vB0, vB1, vB2, vB3;
  LOADKV(0, ka0, ka1, ka2, ka3, vA0, vA1, vA2, vA3);
  bool useA = true;
  for (int t = 0; t <= tmax; ++t) {
    if (useA) {
      if (t < tmax) LOADKV(t + 1, kb0, kb1, kb2, kb3, vB0, vB1, vB2, vB3);
      tile(t == tmax, ka0, ka1, ka2, ka3, vA0, vA1, vA2, vA3);
    } else {
      if (t < tmax) LOADKV(t + 1, ka0, ka1, ka2, ka3, vA0, vA1, vA2, vA3);
      tile(t == tmax, kb0, kb1, kb2, kb3, vB0, vB1, vB2, vB3);
    }
    useA = !useA;
  }
#undef LOADKV

  const int b = bh >> 4, h = bh & (NHEAD - 1);
#pragma unroll
  for (int r = 0; r < 16; ++r) {
    const int crow = (r & 3) + 8 * (r >> 2) + 4 * h5;
    const float lr_ = __builtin_bit_cast(
        float, __builtin_amdgcn_ds_bpermute(crow << 2, __builtin_bit_cast(int, ll)));
    const float inv = __builtin_amdgcn_rcpf(lr_);
    const size_t base = (size_t)(b * S_LEN + qbase + crow) * DMODEL + h * HDIM + lq;
    ctx[base] = f2bf(o0[r] * inv);
    ctx[base + 32] = f2bf(o1[r] * inv);
  }
}

extern "C" void kernel_launch(void* const* d_in, const int* in_sizes, int n_in,
                              void* d_out, int out_size, void* d_ws, size_t ws_size,
                              hipStream_t stream) {
  const float* x = (const float*)d_in[0];
  const float* Wq = (const float*)d_in[1];
  const float* Wk = (const float*)d_in[2];
  const float* Wv = (const float*)d_in[3];
  const float* Wo = (const float*)d_in[4];
  const float* bo = (const float*)d_in[5];

  const size_t XN = (size_t)MROWS * DMODEL;   // 4096*1024
  const size_t WN = (size_t)DMODEL * DMODEL;  // 1024*1024

  short* ws = (short*)d_ws;
  short* xb = ws;
  short* Wqb = xb + XN;   // Wq,Wk,Wv,Wo contiguous ([3072+1024][1024])
  short* Wob = Wqb + 3 * WN;
  short* Qb = Wob + WN;   // Q,K,V contiguous
  short* Kb = Qb + XN;
  short* Vb = Kb + XN;
  short* ctxb = Vb + XN;
  if (ws_size < (5 * XN + 4 * WN) * sizeof(short)) return;

  cvt_kernel<<<2048, 256, 0, stream>>>(x, xb, (int)XN);
  cvt_w4<<<dim3(256, 4), 256, 0, stream>>>(Wq, Wk, Wv, Wo, Wqb);

  gemm_bt<<<dim3(MROWS / 128, 3 * DMODEL / 128), 256, 0, stream>>>(xb, Wqb, Qb, nullptr,
                                                                   nullptr, 4);

  attn_kernel<<<dim3(S_LEN / 128, BATCH * NHEAD), 256, 0, stream>>>(Qb, Kb, Vb, ctxb);

  gemm_bt<<<dim3(MROWS / 128, DMODEL / 128), 256, 0, stream>>>(ctxb, Wob, nullptr,
                                                               (float*)d_out, bo, 3);
}

// Round 3
// 149.886 us; speedup vs baseline: 2.2348x; 1.5097x over previous
//
#include <hip/hip_runtime.h>

#define DEV __device__ __forceinline__

typedef __bf16 bf16x8 __attribute__((ext_vector_type(8)));
typedef float f32x4 __attribute__((ext_vector_type(4)));
typedef float f32x16 __attribute__((ext_vector_type(16)));
typedef unsigned u32x4 __attribute__((ext_vector_type(4)));

constexpr int S_LEN = 2048;
constexpr int DMODEL = 1024;
constexpr int NHEAD = 16;
constexpr int HDIM = 64;
constexpr int BATCH = 2;
constexpr int MROWS = BATCH * S_LEN;  // 4096
constexpr float QSCALE = 0.125f * 1.44269504088896f;  // 1/sqrt(64) * log2(e)

DEV short f2bf(float x) {
  unsigned u = __builtin_bit_cast(unsigned, x);
  unsigned r = u + 0x7fffu + ((u >> 16) & 1u);
  return (short)(r >> 16);
}

#define MFMA16(a, b, c) __builtin_amdgcn_mfma_f32_16x16x32_bf16((a), (b), (c), 0, 0, 0)
#define MFMA32(a, b, c) __builtin_amdgcn_mfma_f32_32x32x16_bf16((a), (b), (c), 0, 0, 0)
#define GLL16(g, l)                                                                     \
  __builtin_amdgcn_global_load_lds((const __attribute__((address_space(1))) void*)(g),  \
                                   (__attribute__((address_space(3))) void*)(l), 16, 0, 0)

DEV unsigned cvt_pk_bf16(float a, float b) {
  unsigned r;
  asm("v_cvt_pk_bf16_f32 %0, %1, %2" : "=v"(r) : "v"(a), "v"(b));
  return r;
}
DEV void swap32(unsigned& a, unsigned& b) {
  asm("v_permlane32_swap_b32 %0, %1" : "+v"(a), "+v"(b));
}

// ---------------- fp32 -> bf16 converts ----------------
__global__ void cvt_kernel(const float* __restrict__ in, short* __restrict__ out, int n) {
  int i = (blockIdx.x * blockDim.x + threadIdx.x) * 4;
  const int stride = gridDim.x * blockDim.x * 4;
  for (; i < n; i += stride) {
    float4 v = *(const float4*)&in[i];
    short4 r;
    r.x = f2bf(v.x);
    r.y = f2bf(v.y);
    r.z = f2bf(v.z);
    r.w = f2bf(v.w);
    *(short4*)&out[i] = r;
  }
}

__global__ void cvt_w4(const float* __restrict__ Wq, const float* __restrict__ Wk,
                       const float* __restrict__ Wv, const float* __restrict__ Wo,
                       short* __restrict__ out) {
  const float* src = blockIdx.y == 0 ? Wq : blockIdx.y == 1 ? Wk : blockIdx.y == 2 ? Wv : Wo;
  short* dst = out + (size_t)blockIdx.y * (DMODEL * DMODEL);
  int i = (blockIdx.x * blockDim.x + threadIdx.x) * 4;
  const int stride = gridDim.x * blockDim.x * 4;
  for (; i < DMODEL * DMODEL; i += stride) {
    float4 v = *(const float4*)&src[i];
    short4 r;
    r.x = f2bf(v.x);
    r.y = f2bf(v.y);
    r.z = f2bf(v.z);
    r.w = f2bf(v.w);
    *(short4*)&dst[i] = r;
  }
}

// ---------------- bf16 GEMM: C[m,e] = sum_k A[m,k] * Bt[e,k] ----------------
// mode 3: out epilogue (fp32 [M,N] + bias)
// mode 4: fused QKV epilogue (Bt is [Wq;Wk;Wv] 3072x1024; outb = Q base, K/V follow)
__global__ __launch_bounds__(256) void gemm_bt(const short* __restrict__ A,
                                               const short* __restrict__ Bt,
                                               short* __restrict__ outb,
                                               float* __restrict__ outf,
                                               const float* __restrict__ bias,
                                               const int mode) {
  constexpr int K = DMODEL;
  constexpr int N = DMODEL;
  constexpr size_t XN = (size_t)MROWS * DMODEL;
  __shared__ short As[128 * 32];
  __shared__ short Bs[128 * 32];
  const int tid = threadIdx.x;
  const int w = tid >> 6, l = tid & 63;
  const int lr = l & 15, lh = l >> 4;
  const int wr = w >> 1, wc = w & 1;
  const int tm = blockIdx.x, tn = blockIdx.y;

  f32x4 acc[4][4] = {};

  for (int kt = 0; kt < K / 32; ++kt) {
#pragma unroll
    for (int r = 0; r < 2; ++r) {
      const int c = r * 256 + tid;
      const int row = c >> 2;
      const int kc = (c & 3) * 8;
      GLL16(A + (size_t)(tm * 128 + row) * K + kt * 32 + kc, &As[(r * 256 + w * 64) * 8]);
      GLL16(Bt + (size_t)(tn * 128 + row) * K + kt * 32 + kc, &Bs[(r * 256 + w * 64) * 8]);
    }
    __syncthreads();
    bf16x8 af[4], bfr[4];
#pragma unroll
    for (int mi = 0; mi < 4; ++mi)
      af[mi] = *(const bf16x8*)&As[(wr * 64 + mi * 16 + lr) * 32 + lh * 8];
#pragma unroll
    for (int ni = 0; ni < 4; ++ni)
      bfr[ni] = *(const bf16x8*)&Bs[(wc * 64 + ni * 16 + lr) * 32 + lh * 8];
#pragma unroll
    for (int mi = 0; mi < 4; ++mi)
#pragma unroll
      for (int ni = 0; ni < 4; ++ni)
        acc[mi][ni] = MFMA16(af[mi], bfr[ni], acc[mi][ni]);
    __syncthreads();
  }

  // C/D frag layout: row = (l>>4)*4 + i, col = l&15
  const int m0 = tm * 128 + wr * 64;
  const int n0 = tn * 128 + wc * 64;
  if (mode == 3) {
#pragma unroll
    for (int mi = 0; mi < 4; ++mi)
#pragma unroll
      for (int ni = 0; ni < 4; ++ni)
#pragma unroll
        for (int i = 0; i < 4; ++i) {
          const int m = m0 + mi * 16 + lh * 4 + i;
          const int e = n0 + ni * 16 + lr;
          outf[(size_t)m * N + e] = acc[mi][ni][i] + bias[e];
        }
  } else {  // fused QKV
    const int sel = tn >> 3;
#pragma unroll
    for (int mi = 0; mi < 4; ++mi)
#pragma unroll
      for (int ni = 0; ni < 4; ++ni)
#pragma unroll
        for (int i = 0; i < 4; ++i) {
          const int m = m0 + mi * 16 + lh * 4 + i;
          const int e = n0 + ni * 16 + lr;
          const int ecol = e & (DMODEL - 1);
          const int b = m >> 11, n = m & (S_LEN - 1);
          const int h = ecol >> 6, d = ecol & (HDIM - 1);
          if (sel == 0)
            outb[((size_t)((b * NHEAD + h) * S_LEN + n)) * HDIM + d] =
                f2bf(acc[mi][ni][i] * QSCALE);
          else if (sel == 1)
            (outb + XN)[((size_t)((b * NHEAD + h) * S_LEN + n)) * HDIM + d] =
                f2bf(acc[mi][ni][i]);
          else
            (outb + 2 * XN)[((size_t)((b * NHEAD + h) * HDIM + d)) * S_LEN + n] =
                f2bf(acc[mi][ni][i]);
        }
  }
}

// swizzled LDS fragment read: 16B at slot (0..7) of a 128B row, slot ^= row&7
DEV bf16x8 ldsfrag(const short* base, int row, int slot) {
  return *(const bf16x8*)&base[row * 64 + 8 * (slot ^ (row & 7))];
}

// ---------------- flash attention, swapped-QK^T 32x32, LDS-staged KV ----------------
// grid: (S/128, B*H), 4 waves/block; wave owns 32 q rows; KV tile = 64 (2 st chains).
// Q pre-scaled by log2(e)/8. K layout [B,H,S,HD]; V layout [B,H,HD,S] (= V^T rows).
__global__ __launch_bounds__(256) void attn_kernel(const short* __restrict__ Qg,
                                                   const short* __restrict__ Kg,
                                                   const short* __restrict__ Vg,
                                                   short* __restrict__ ctx) {
  __shared__ alignas(16) short Ks[2][64 * 64];
  __shared__ alignas(16) short Vs[2][64 * 64];
  const int tid = threadIdx.x;
  const int w = tid >> 6;
  const int l = tid & 63;
  const int lq = l & 31;
  const int h5 = l >> 5;
  const int bh = blockIdx.y;
  const int qb0 = (gridDim.x - 1 - blockIdx.x) * 128;  // big blocks first
  const int qbase = qb0 + w * 32;
  const short* Qh = Qg + (size_t)bh * (S_LEN * HDIM);
  const short* Kh = Kg + (size_t)bh * (S_LEN * HDIM);
  const short* Vh = Vg + (size_t)bh * (HDIM * S_LEN);

  // staging lane constants: rows w*16..w*16+15 per wave, pre-swizzled global src
  const int srow0 = (w * 2) * 8 + (l >> 3);  // instr i adds 8
  const int scol = l & 7;

  // Q as B-operand: lane holds Q[qbase+lq][c*16 + h5*8 + j]
  bf16x8 qf[4];
#pragma unroll
  for (int c = 0; c < 4; ++c)
    qf[c] = *(const bf16x8*)&Qh[(size_t)(qbase + lq) * HDIM + c * 16 + h5 * 8];

  f32x16 o0 = {}, o1 = {};
  float m = -__builtin_inff(), ll = 0.f;

  const int tmax_w = qbase >> 6;
  const int tmax_blk = (qb0 >> 6) + 1;

#define STAGE(T, BUF)                                                                \
  {                                                                                  \
    _Pragma("unroll") for (int i = 0; i < 2; ++i) {                                  \
      const int r = srow0 + i * 8;                                                   \
      const int sw = 8 * (scol ^ (r & 7));                                           \
      GLL16(Kh + (size_t)((T)*64 + r) * HDIM + sw, &Ks[BUF][(w * 2 + i) * 8 * 64]);  \
      GLL16(Vh + (size_t)r * S_LEN + (T)*64 + sw, &Vs[BUF][(w * 2 + i) * 8 * 64]);   \
    }                                                                                \
  }

  STAGE(0, 0);
  asm volatile("s_waitcnt vmcnt(0)" ::: "memory");
  __syncthreads();

  for (int t = 0; t <= tmax_blk; ++t) {
    const int buf = t & 1;
    if (t < tmax_blk) STAGE(t + 1, buf ^ 1);

    if (t <= tmax_w) {
      const short* Ksb = Ks[buf];
      const short* Vsb = Vs[buf];
      // ---- QK^T (two 32-kv sub-tiles) ----
      bf16x8 kf[4];
#pragma unroll
      for (int c = 0; c < 4; ++c) kf[c] = ldsfrag(Ksb, lq, c * 2 + h5);
      f32x16 st0 = {};
#pragma unroll
      for (int c = 0; c < 4; ++c) st0 = MFMA32(kf[c], qf[c], st0);
#pragma unroll
      for (int c = 0; c < 4; ++c) kf[c] = ldsfrag(Ksb, 32 + lq, c * 2 + h5);
      f32x16 st1 = {};
#pragma unroll
      for (int c = 0; c < 4; ++c) st1 = MFMA32(kf[c], qf[c], st1);

      if (t == tmax_w) {  // diagonal tile: mask kr > q
        const int qg = qbase + lq;
#pragma unroll
        for (int r = 0; r < 16; ++r) {
          const int crow = (r & 3) + 8 * (r >> 2) + 4 * h5;
          if (t * 64 + crow > qg) st0[r] = -__builtin_inff();
          if (t * 64 + 32 + crow > qg) st1[r] = -__builtin_inff();
        }
      }
      // ---- online softmax (per q-column = lane) ----
      float pm = fmaxf(st0[0], st1[0]);
#pragma unroll
      for (int r = 1; r < 16; ++r) pm = fmaxf(pm, fmaxf(st0[r], st1[r]));
      pm = fmaxf(pm, __shfl_xor(pm, 32));
      if (__any(pm - m > 8.f)) {  // defer-max
        const float nm = fmaxf(m, pm);
        const float f = __builtin_amdgcn_exp2f(m - nm);
        m = nm;
        ll *= f;
#pragma unroll
        for (int r = 0; r < 16; ++r) {
          const int srcb = ((r & 3) + 8 * (r >> 2) + 4 * h5) << 2;
          const float fr = __builtin_bit_cast(
              float, __builtin_amdgcn_ds_bpermute(srcb, __builtin_bit_cast(int, f)));
          o0[r] *= fr;
          o1[r] *= fr;
        }
      }
      float ps = 0.f;
#pragma unroll
      for (int r = 0; r < 16; ++r) {
        st0[r] = __builtin_amdgcn_exp2f(st0[r] - m);
        st1[r] = __builtin_amdgcn_exp2f(st1[r] - m);
        ps += st0[r] + st1[r];
      }
      ps += __shfl_xor(ps, 32);
      ll += ps;
      // ---- pack P -> A-operand frags (cvt_pk + permlane32_swap) ----
      unsigned a0 = cvt_pk_bf16(st0[0], st0[1]), b0 = cvt_pk_bf16(st0[4], st0[5]);
      unsigned a1 = cvt_pk_bf16(st0[2], st0[3]), b1 = cvt_pk_bf16(st0[6], st0[7]);
      unsigned a2 = cvt_pk_bf16(st0[8], st0[9]), b2 = cvt_pk_bf16(st0[12], st0[13]);
      unsigned a3 = cvt_pk_bf16(st0[10], st0[11]), b3 = cvt_pk_bf16(st0[14], st0[15]);
      unsigned c0 = cvt_pk_bf16(st1[0], st1[1]), d0 = cvt_pk_bf16(st1[4], st1[5]);
      unsigned c1 = cvt_pk_bf16(st1[2], st1[3]), d1 = cvt_pk_bf16(st1[6], st1[7]);
      unsigned c2 = cvt_pk_bf16(st1[8], st1[9]), d2 = cvt_pk_bf16(st1[12], st1[13]);
      unsigned c3 = cvt_pk_bf16(st1[10], st1[11]), d3 = cvt_pk_bf16(st1[14], st1[15]);
      swap32(a0, b0);
      swap32(a1, b1);
      swap32(a2, b2);
      swap32(a3, b3);
      swap32(c0, d0);
      swap32(c1, d1);
      swap32(c2, d2);
      swap32(c3, d3);
      const u32x4 pw0 = {a0, a1, b0, b1};
      const u32x4 pw1 = {a2, a3, b2, b3};
      const u32x4 pw2 = {c0, c1, d0, d1};
      const u32x4 pw3 = {c2, c3, d2, d3};
      bf16x8 pa[4] = {__builtin_bit_cast(bf16x8, pw0), __builtin_bit_cast(bf16x8, pw1),
                      __builtin_bit_cast(bf16x8, pw2), __builtin_bit_cast(bf16x8, pw3)};
      // ---- PV ----
#pragma unroll
      for (int s = 0; s < 2; ++s)
#pragma unroll
        for (int c2i = 0; c2i < 2; ++c2i) {
          const int slot = s * 4 + c2i * 2 + h5;
          o0 = MFMA32(pa[s * 2 + c2i], ldsfrag(Vsb, lq, slot), o0);
          o1 = MFMA32(pa[s * 2 + c2i], ldsfrag(Vsb, 32 + lq, slot), o1);
        }
    }

    asm volatile("s_waitcnt vmcnt(0)" ::: "memory");
    __syncthreads();
  }
#undef STAGE

  const int b = bh >> 4, h = bh & (NHEAD - 1);
#pragma unroll
  for (int r = 0; r < 16; ++r) {
    const int crow = (r & 3) + 8 * (r >> 2) + 4 * h5;
    const float lr_ = __builtin_bit_cast(
        float, __builtin_amdgcn_ds_bpermute(crow << 2, __builtin_bit_cast(int, ll)));
    const float inv = __builtin_amdgcn_rcpf(lr_);
    const size_t base = (size_t)(b * S_LEN + qbase + crow) * DMODEL + h * HDIM + lq;
    ctx[base] = f2bf(o0[r] * inv);
    ctx[base + 32] = f2bf(o1[r] * inv);
  }
}

extern "C" void kernel_launch(void* const* d_in, const int* in_sizes, int n_in,
                              void* d_out, int out_size, void* d_ws, size_t ws_size,
                              hipStream_t stream) {
  const float* x = (const float*)d_in[0];
  const float* Wq = (const float*)d_in[1];
  const float* Wk = (const float*)d_in[2];
  const float* Wv = (const float*)d_in[3];
  const float* Wo = (const float*)d_in[4];
  const float* bo = (const float*)d_in[5];

  const size_t XN = (size_t)MROWS * DMODEL;   // 4096*1024
  const size_t WN = (size_t)DMODEL * DMODEL;  // 1024*1024

  short* ws = (short*)d_ws;
  short* xb = ws;
  short* Wqb = xb + XN;  // Wq,Wk,Wv,Wo contiguous ([3072+1024][1024])
  short* Wob = Wqb + 3 * WN;
  short* Qb = Wob + WN;  // Q,K,V contiguous
  short* Kb = Qb + XN;
  short* Vb = Kb + XN;
  short* ctxb = Vb + XN;
  if (ws_size < (5 * XN + 4 * WN) * sizeof(short)) return;

  cvt_kernel<<<2048, 256, 0, stream>>>(x, xb, (int)XN);
  cvt_w4<<<dim3(256, 4), 256, 0, stream>>>(Wq, Wk, Wv, Wo, Wqb);

  gemm_bt<<<dim3(MROWS / 128, 3 * DMODEL / 128), 256, 0, stream>>>(xb, Wqb, Qb, nullptr,
                                                                   nullptr, 4);

  attn_kernel<<<dim3(S_LEN / 128, BATCH * NHEAD), 256, 0, stream>>>(Qb, Kb, Vb, ctxb);

  gemm_bt<<<dim3(MROWS / 128, DMODEL / 128), 256, 0, stream>>>(ctxb, Wob, nullptr,
                                                               (float*)d_out, bo, 3);
}